// Round 5
// baseline (831.460 us; speedup 1.0000x reference)
//
#include <hip/hip_runtime.h>

#define KCODES 4096
#define NROWS  32768
#define DIM    256
#define MB     64    // rows per block (stage 1)
#define LDA    264   // bf16 elems per LDS A row (256 + 8 pad)

typedef __attribute__((ext_vector_type(8))) short  short8;
typedef __attribute__((ext_vector_type(4))) float  float4v;

__device__ inline unsigned short f2bf(float f) {
    unsigned u = __float_as_uint(f);
    unsigned r = (u >> 16) & 1u;
    return (unsigned short)((u + 0x7FFFu + r) >> 16);   // RNE
}
__device__ inline float bf2f(unsigned short h) {
    return __uint_as_float(((unsigned)h) << 16);
}

// ---------------- kernel 0: codebook squared norms — VERBATIM R1 recipe ----------------
__global__ __launch_bounds__(256) void csq_kernel(const float* __restrict__ cb,
                                                  float* __restrict__ csq) {
    int code = blockIdx.x * 256 + threadIdx.x;
    if (code < KCODES) {
        const float4* row = (const float4*)(cb + (size_t)code * DIM);
        float s = 0.f;
        #pragma unroll 8
        for (int i = 0; i < DIM / 4; ++i) {
            float4 v = row[i];
            s += v.x * v.x + v.y * v.y + v.z * v.z + v.w * v.w;
        }
        csq[code] = s;
    }
}

// ---------------- kernel 1: cb -> bf16 hi/lo planes in MFMA-fragment order ----------------
// chunk ci = (kb*8 + ks)*64 + lane ; holds codes kb*16+(lane&15), dims ks*32+(lane>>4)*8 ..+8
__global__ __launch_bounds__(256) void convert_kernel(const float* __restrict__ cb,
                                                      unsigned short* __restrict__ cbhF,
                                                      unsigned short* __restrict__ cblF) {
    const int ci = blockIdx.x * 256 + threadIdx.x;   // 0 .. 131071
    const int lane = ci & 63;
    const int kbks = ci >> 6;
    const int ks = kbks & 7, kb = kbks >> 3;
    const int code = kb * 16 + (lane & 15);
    const int dim  = ks * 32 + (lane >> 4) * 8;
    const float* src = cb + (size_t)code * DIM + dim;
    float4 v0 = *(const float4*)src;
    float4 v1 = *(const float4*)(src + 4);
    float vals[8] = { v0.x, v0.y, v0.z, v0.w, v1.x, v1.y, v1.z, v1.w };
    short8 hv, lv;
    #pragma unroll
    for (int i = 0; i < 8; ++i) {
        unsigned short h = f2bf(vals[i]);
        hv[i] = (short)h;
        lv[i] = (short)f2bf(vals[i] - bf2f(h));
    }
    *(short8*)(cbhF + (size_t)ci * 8) = hv;
    *(short8*)(cblF + (size_t)ci * 8) = lv;
}

// ---------------- kernel 2: split-bf16 MFMA GEMM, top-2 per code-half -> 4 cands ----------------
__global__ __launch_bounds__(256, 2) void gemm_top4_kernel(const float* __restrict__ x,
                                                           const unsigned short* __restrict__ cbhF,
                                                           const unsigned short* __restrict__ cblF,
                                                           const float* __restrict__ csq,
                                                           int* __restrict__ top4) {
    __shared__ unsigned short sAh[MB * LDA];
    __shared__ unsigned short sAl[MB * LDA];
    __shared__ int mI1[2][MB];
    __shared__ int mI2[2][MB];

    const int tid = threadIdx.x;
    const int lane = tid & 63, wid = tid >> 6;
    const int wm = wid >> 1, wn = wid & 1;      // 2x2 wave grid: 32 rows x 64 codes per wave
    const int c = lane & 15, q = lane >> 4;
    const int rowBase = blockIdx.x * MB;

    // ---- stage A (x rows) as hi/lo bf16 into LDS, once ----
    const float4* x4 = (const float4*)x;
    #pragma unroll
    for (int i = 0; i < 16; ++i) {
        int f = tid + i * 256;
        int r = f >> 6, c4 = f & 63;
        float4 v = x4[(size_t)(rowBase + r) * 64 + c4];
        ushort4 h = { f2bf(v.x), f2bf(v.y), f2bf(v.z), f2bf(v.w) };
        ushort4 l = { f2bf(v.x - bf2f(h.x)), f2bf(v.y - bf2f(h.y)),
                      f2bf(v.z - bf2f(h.z)), f2bf(v.w - bf2f(h.w)) };
        *(ushort4*)&sAh[r * LDA + c4 * 4] = h;
        *(ushort4*)&sAl[r * LDA + c4 * 4] = l;
    }
    __syncthreads();

    // per-lane top-2 for the 8 (mi,r) row-slots
    float v1[8], v2[8]; int i1[8], i2[8];
    #pragma unroll
    for (int s = 0; s < 8; ++s) { v1[s] = INFINITY; v2[s] = INFINITY; i1[s] = 0x7FFFFFFF; i2[s] = 0x7FFFFFFF; }

    for (int ct = 0; ct < KCODES / 128; ++ct) {
        const int codeBase = ct * 128;
        float4v acc[2][4];
        #pragma unroll
        for (int mi = 0; mi < 2; ++mi)
            #pragma unroll
            for (int ni = 0; ni < 4; ++ni)
                #pragma unroll
                for (int e = 0; e < 4; ++e) acc[mi][ni][e] = 0.f;

        #pragma unroll
        for (int ks = 0; ks < 8; ++ks) {
            short8 ah[2], al[2], bh[4], bl[4];
            #pragma unroll
            for (int ni = 0; ni < 4; ++ni) {
                // fragment-ordered: kb = ct*8 + wn*4 + ni
                size_t fo = (((size_t)(ct * 8 + wn * 4 + ni) * 8 + ks) * 64 + lane) * 8;
                bh[ni] = *(const short8*)(cbhF + fo);
                bl[ni] = *(const short8*)(cblF + fo);
            }
            #pragma unroll
            for (int mi = 0; mi < 2; ++mi) {
                int aoff = (wm * 32 + mi * 16 + c) * LDA + ks * 32 + q * 8;
                ah[mi] = *(const short8*)&sAh[aoff];
                al[mi] = *(const short8*)&sAl[aoff];
            }
            #pragma unroll
            for (int mi = 0; mi < 2; ++mi)
                #pragma unroll
                for (int ni = 0; ni < 4; ++ni) {
                    acc[mi][ni] = __builtin_amdgcn_mfma_f32_16x16x32_bf16(ah[mi], bh[ni], acc[mi][ni], 0, 0, 0);
                    acc[mi][ni] = __builtin_amdgcn_mfma_f32_16x16x32_bf16(ah[mi], bl[ni], acc[mi][ni], 0, 0, 0);
                    acc[mi][ni] = __builtin_amdgcn_mfma_f32_16x16x32_bf16(al[mi], bh[ni], acc[mi][ni], 0, 0, 0);
                }
        }

        // ---- epilogue: dist = csq - 2*dot ; top-2 update ----
        float cs[4];
        #pragma unroll
        for (int ni = 0; ni < 4; ++ni) cs[ni] = csq[codeBase + wn * 64 + ni * 16 + c];
        #pragma unroll
        for (int mi = 0; mi < 2; ++mi)
            #pragma unroll
            for (int r = 0; r < 4; ++r) {
                const int s = mi * 4 + r;
                #pragma unroll
                for (int ni = 0; ni < 4; ++ni) {
                    float d = fmaf(-2.f, acc[mi][ni][r], cs[ni]);
                    int   k = codeBase + wn * 64 + ni * 16 + c;
                    bool b1 = d < v1[s];
                    bool b2 = d < v2[s];
                    v2[s] = b1 ? v1[s] : (b2 ? d : v2[s]);
                    i2[s] = b1 ? i1[s] : (b2 ? k : i2[s]);
                    v1[s] = b1 ? d : v1[s];
                    i1[s] = b1 ? k : i1[s];
                }
            }
    }

    // ---- butterfly lex-merge of top-2 across the 16 code-lanes (per half) ----
    #pragma unroll
    for (int s = 0; s < 8; ++s) {
        float a1 = v1[s], a2 = v2[s]; int b1 = i1[s], b2 = i2[s];
        #pragma unroll
        for (int m = 1; m < 16; m <<= 1) {
            float w1 = __shfl_xor(a1, m), w2 = __shfl_xor(a2, m);
            int   j1 = __shfl_xor(b1, m), j2 = __shfl_xor(b2, m);
            bool lt = (w1 < a1) || (w1 == a1 && j1 < b1);
            float f1 = lt ? w1 : a1;  int g1 = lt ? j1 : b1;   // merged first
            float o1 = lt ? a1 : w1;  int p1 = lt ? b1 : j1;   // loser of firsts
            float o2 = lt ? w2 : a2;  int p2 = lt ? j2 : b2;   // winner's second
            bool lt2 = (o1 < o2) || (o1 == o2 && p1 < p2);
            a1 = f1; b1 = g1;
            a2 = lt2 ? o1 : o2; b2 = lt2 ? p1 : p2;
        }
        if (c == 0) {
            int row = wm * 32 + (s >> 2) * 16 + q * 4 + (s & 3);
            mI1[wn][row] = b1;
            mI2[wn][row] = b2;
        }
    }
    __syncthreads();

    // ---- emit 4 candidates per row (top-2 of each code half) ----
    if (tid < MB) {
        size_t rg = (size_t)(rowBase + tid) * 4;
        top4[rg + 0] = mI1[0][tid];
        top4[rg + 1] = mI2[0][tid];
        top4[rg + 2] = mI1[1][tid];
        top4[rg + 3] = mI2[1][tid];
    }
}

// ---------------- kernel 3: rescore with R1's exact fp32 recipe + gather + loss ----------------
__global__ __launch_bounds__(256) void rescore_kernel(const float* __restrict__ x,
                                                      const float* __restrict__ cb,
                                                      const float* __restrict__ csq,
                                                      const int* __restrict__ top4,
                                                      float* __restrict__ out,
                                                      float* __restrict__ partial) {
    __shared__ float sx[64 * 256];   // 64 rows of x, raw fp32
    __shared__ float rv[64][4];
    __shared__ int   rk[64][4];
    __shared__ int   pick[64];
    __shared__ float sred[256];

    const int tid = threadIdx.x;
    const int rowBase = blockIdx.x * 64;
    const float4* x4 = (const float4*)x;
    const float4* c4 = (const float4*)cb;

    // stage 64 x-rows (coalesced float4)
    #pragma unroll
    for (int i = 0; i < 16; ++i) {
        int g = tid + i * 256;
        ((float4*)sx)[g] = x4[(size_t)rowBase * 64 + g];
    }
    __syncthreads();

    // one thread per (row, candidate): serial fmaf chain, ascending d (bit-identical to R1)
    {
        const int r = tid >> 2, ci = tid & 3;
        const int k = top4[(size_t)(rowBase + r) * 4 + ci];
        const float4* cr = c4 + (size_t)k * 64;
        const float4* xr = (const float4*)sx + r * 64;
        float acc = 0.f;
        for (int d4 = 0; d4 < 64; ++d4) {
            float4 cv = cr[d4];
            float4 xv = xr[d4];
            acc = fmaf(xv.x, cv.x, acc);
            acc = fmaf(xv.y, cv.y, acc);
            acc = fmaf(xv.z, cv.z, acc);
            acc = fmaf(xv.w, cv.w, acc);
        }
        float cs = csq[k];
        float v = cs - 2.0f * acc;    // same expression as R1
        rv[r][ci] = v;
        rk[r][ci] = k;
    }
    __syncthreads();

    // lex-min over the 4 candidates (R1's comparator)
    if (tid < 64) {
        float bv = rv[tid][0];
        int   bi = rk[tid][0];
        #pragma unroll
        for (int t = 1; t < 4; ++t) {
            float v = rv[tid][t];
            int  ii = rk[tid][t];
            if (v < bv || (v == bv && ii < bi)) { bv = v; bi = ii; }
        }
        pick[tid] = bi;
    }
    __syncthreads();

    // gather + loss partial
    float s = 0.f;
    #pragma unroll
    for (int i = 0; i < 16; ++i) {
        int g = tid + i * 256;
        int r = g >> 6, col = g & 63;
        int k = pick[r];
        float4 cv = c4[(size_t)k * 64 + col];
        float4 xv = ((const float4*)sx)[g];
        ((float4*)out)[(size_t)rowBase * 64 + g] = cv;
        float dx = cv.x - xv.x, dy = cv.y - xv.y, dz = cv.z - xv.z, dw = cv.w - xv.w;
        s += dx * dx + dy * dy + dz * dz + dw * dw;
    }
    sred[tid] = s;
    __syncthreads();
    for (int off = 128; off > 0; off >>= 1) {
        if (tid < off) sred[tid] += sred[tid + off];
        __syncthreads();
    }
    if (tid == 0) partial[blockIdx.x] = sred[0];
}

// ---------------- kernel 4: finalize loss ----------------
__global__ __launch_bounds__(256) void finalize_kernel(const float* __restrict__ partial,
                                                       float* __restrict__ loss_out) {
    __shared__ float sred[256];
    const int tid = threadIdx.x;
    float s = 0.f;
    for (int i = tid; i < 512; i += 256) s += partial[i];
    sred[tid] = s;
    __syncthreads();
    for (int off = 128; off > 0; off >>= 1) {
        if (tid < off) sred[tid] += sred[tid + off];
        __syncthreads();
    }
    if (tid == 0) loss_out[0] = sred[0] * 1.25f / 8388608.0f;
}

extern "C" void kernel_launch(void* const* d_in, const int* in_sizes, int n_in,
                              void* d_out, int out_size, void* d_ws, size_t ws_size,
                              hipStream_t stream) {
    const float* x  = (const float*)d_in[0];
    const float* cb = (const float*)d_in[1];
    float* out = (float*)d_out;

    char* ws = (char*)d_ws;
    unsigned short* cbhF = (unsigned short*)ws;                       // 2 MB
    unsigned short* cblF = (unsigned short*)(ws + 2097152);           // 2 MB
    float* csq           = (float*)(ws + 4194304);                    // 16 KB
    int*   top4          = (int*)(ws + 4194304 + 16384);              // 512 KB
    float* partial       = (float*)(ws + 4194304 + 16384 + 524288);   // 2 KB

    csq_kernel<<<KCODES / 256, 256, 0, stream>>>(cb, csq);
    convert_kernel<<<512, 256, 0, stream>>>(cb, cbhF, cblF);
    gemm_top4_kernel<<<NROWS / MB, 256, 0, stream>>>(x, cbhF, cblF, csq, top4);
    rescore_kernel<<<NROWS / 64, 256, 0, stream>>>(x, cb, csq, top4, out, partial);
    finalize_kernel<<<1, 256, 0, stream>>>(partial, out + 8388608);
}

// Round 6
// 390.408 us; speedup vs baseline: 2.1297x; 2.1297x over previous
//
#include <hip/hip_runtime.h>

#define KCODES 4096
#define NROWS  32768
#define DIM    256
#define K2     512          // [hi | lo] concat K
#define BM     128
#define BN     128
#define BK     64           // bf16 elems per K chunk
#define NKT    (K2 / BK)    // 8
#define NJT    (KCODES / BN) // 32

typedef __attribute__((ext_vector_type(8))) short  short8;
typedef __attribute__((ext_vector_type(4))) float  float4v;

__device__ inline unsigned short f2bf(float f) {
    unsigned u = __float_as_uint(f);
    unsigned r = (u >> 16) & 1u;
    return (unsigned short)((u + 0x7FFFu + r) >> 16);   // RNE
}
__device__ inline float bf2f(unsigned short h) {
    return __uint_as_float(((unsigned)h) << 16);
}
__device__ inline void load_lds16(const void* g, void* l) {
    __builtin_amdgcn_global_load_lds((const __attribute__((address_space(1))) void*)g,
                                     (__attribute__((address_space(3))) void*)l, 16, 0, 0);
}

// ---------------- kernel 0: codebook squared norms — VERBATIM R1 recipe ----------------
__global__ __launch_bounds__(256) void csq_kernel(const float* __restrict__ cb,
                                                  float* __restrict__ csq) {
    int code = blockIdx.x * 256 + threadIdx.x;
    if (code < KCODES) {
        const float4* row = (const float4*)(cb + (size_t)code * DIM);
        float s = 0.f;
        #pragma unroll 8
        for (int i = 0; i < DIM / 4; ++i) {
            float4 v = row[i];
            s += v.x * v.x + v.y * v.y + v.z * v.z + v.w * v.w;
        }
        csq[code] = s;
    }
}

// ---------------- kernel 1: fp32 (rows x 256) -> bf16 [hi|lo] (rows x 512) ----------------
__global__ __launch_bounds__(256) void conv_kernel(const float* __restrict__ src,
                                                   unsigned short* __restrict__ dst) {
    const int idx = blockIdx.x * 256 + threadIdx.x;   // one float4 per thread
    const int row = idx >> 6, c4 = idx & 63;
    float4 v = ((const float4*)src)[idx];
    ushort4 h = { f2bf(v.x), f2bf(v.y), f2bf(v.z), f2bf(v.w) };
    ushort4 l = { f2bf(v.x - bf2f(h.x)), f2bf(v.y - bf2f(h.y)),
                  f2bf(v.z - bf2f(h.z)), f2bf(v.w - bf2f(h.w)) };
    ((ushort4*)dst)[(size_t)row * 128 + c4]      = h;   // hi half: k = c4*4
    ((ushort4*)dst)[(size_t)row * 128 + 64 + c4] = l;   // lo half: k = 256 + c4*4
}

// ---------------- kernel 2: K=512 bf16 GEMM (m97 structure) + per-tile top-2 ----------------
// grid = 8192: j = bid & 31 (N-tile, inner for B L2 residency), mB = bid >> 5
__global__ __launch_bounds__(256, 3) void gemm_top2_kernel(const unsigned short* __restrict__ A2,
                                                           const unsigned short* __restrict__ B2,
                                                           const float* __restrict__ csq,
                                                           float4* __restrict__ pairs) {
    __shared__ unsigned short sA[BM * BK];   // 16 KB, slot = r*8 + (kg ^ (r&7)), 8 bf16/slot
    __shared__ unsigned short sB[BN * BK];
    __shared__ float sV1[2][BM]; __shared__ int sI1[2][BM];
    __shared__ float sV2[2][BM]; __shared__ int sI2[2][BM];

    const int tid = threadIdx.x;
    const int lane = tid & 63, wid = tid >> 6;
    const int wm = wid >> 1, wn = wid & 1;
    const int c = lane & 15, q = lane >> 4;
    const int j = blockIdx.x & (NJT - 1);
    const int mB = blockIdx.x >> 5;
    const int mBase = mB * BM, jBase = j * BN;

    // staging descriptors: 4 A-slots + 4 B-slots per lane
    size_t gA[4], gB[4];
    int    ldsOff[4];
    #pragma unroll
    for (int i = 0; i < 4; ++i) {
        int s  = wid * 256 + i * 64 + lane;   // slot 0..1023
        int r  = s >> 3, kgp = s & 7;
        int kg = kgp ^ (r & 7);
        gA[i] = (size_t)(mBase + r) * K2 + kg * 8;
        gB[i] = (size_t)(jBase + r) * K2 + kg * 8;
        ldsOff[i] = (wid * 256 + i * 64) * 8;  // wave-uniform ushort offset
    }

    float4v acc[4][4];
    #pragma unroll
    for (int mi = 0; mi < 4; ++mi)
        #pragma unroll
        for (int ni = 0; ni < 4; ++ni)
            #pragma unroll
            for (int e = 0; e < 4; ++e) acc[mi][ni][e] = 0.f;

    for (int kt = 0; kt < NKT; ++kt) {
        const int kOff = kt * BK;
        #pragma unroll
        for (int i = 0; i < 4; ++i) {
            load_lds16(A2 + gA[i] + kOff, &sA[ldsOff[i]]);
            load_lds16(B2 + gB[i] + kOff, &sB[ldsOff[i]]);
        }
        __syncthreads();   // vmcnt(0) drain + barrier

        #pragma unroll
        for (int ks = 0; ks < 2; ++ks) {
            short8 aF[4], bF[4];
            #pragma unroll
            for (int mi = 0; mi < 4; ++mi) {
                int r  = wm * 64 + mi * 16 + c;
                int kg = ks * 4 + q;
                aF[mi] = *(const short8*)&sA[(r * 8 + (kg ^ (r & 7))) * 8];
            }
            #pragma unroll
            for (int ni = 0; ni < 4; ++ni) {
                int r  = wn * 64 + ni * 16 + c;
                int kg = ks * 4 + q;
                bF[ni] = *(const short8*)&sB[(r * 8 + (kg ^ (r & 7))) * 8];
            }
            #pragma unroll
            for (int mi = 0; mi < 4; ++mi)
                #pragma unroll
                for (int ni = 0; ni < 4; ++ni)
                    acc[mi][ni] = __builtin_amdgcn_mfma_f32_16x16x32_bf16(aF[mi], bF[ni], acc[mi][ni], 0, 0, 0);
        }
        __syncthreads();   // protect LDS before next stage
    }

    // ---- epilogue: dist = csq - 2*dot ; per-(row, tile) top-2 ----
    float cs[4];
    #pragma unroll
    for (int ni = 0; ni < 4; ++ni) cs[ni] = csq[jBase + wn * 64 + ni * 16 + c];

    #pragma unroll
    for (int mi = 0; mi < 4; ++mi)
        #pragma unroll
        for (int r = 0; r < 4; ++r) {
            float a1 = INFINITY, a2 = INFINITY; int b1 = 0x7FFFFFFF, b2 = 0x7FFFFFFF;
            #pragma unroll
            for (int ni = 0; ni < 4; ++ni) {
                float d = fmaf(-2.f, acc[mi][ni][r], cs[ni]);
                int   k = jBase + wn * 64 + ni * 16 + c;
                bool f1 = d < a1;
                bool f2 = d < a2;
                a2 = f1 ? a1 : (f2 ? d : a2);
                b2 = f1 ? b1 : (f2 ? k : b2);
                a1 = f1 ? d : a1;
                b1 = f1 ? k : b1;
            }
            // butterfly lex-merge of top-2 over the 16 c-lanes
            #pragma unroll
            for (int m = 1; m < 16; m <<= 1) {
                float w1 = __shfl_xor(a1, m), w2 = __shfl_xor(a2, m);
                int   j1 = __shfl_xor(b1, m), j2 = __shfl_xor(b2, m);
                bool lt = (w1 < a1) || (w1 == a1 && j1 < b1);
                float f1v = lt ? w1 : a1;  int g1 = lt ? j1 : b1;
                float o1 = lt ? a1 : w1;   int p1 = lt ? b1 : j1;
                float o2 = lt ? w2 : a2;   int p2 = lt ? j2 : b2;
                bool lt2 = (o1 < o2) || (o1 == o2 && p1 < p2);
                a1 = f1v; b1 = g1;
                a2 = lt2 ? o1 : o2; b2 = lt2 ? p1 : p2;
            }
            if (c == 0) {
                int row = wm * 64 + mi * 16 + q * 4 + r;
                sV1[wn][row] = a1; sI1[wn][row] = b1;
                sV2[wn][row] = a2; sI2[wn][row] = b2;
            }
        }
    __syncthreads();

    // merge the two code-halves, write (v1,i1,v2,i2) per row for this tile
    if (tid < BM) {
        float a1 = sV1[0][tid], a2 = sV2[0][tid];
        int   b1 = sI1[0][tid], b2 = sI2[0][tid];
        float w1 = sV1[1][tid], w2 = sV2[1][tid];
        int   j1 = sI1[1][tid], j2 = sI2[1][tid];
        bool lt = (w1 < a1) || (w1 == a1 && j1 < b1);
        float f1 = lt ? w1 : a1;  int g1 = lt ? j1 : b1;
        float o1 = lt ? a1 : w1;  int p1 = lt ? b1 : j1;
        float o2 = lt ? w2 : a2;  int p2 = lt ? j2 : b2;
        bool lt2 = (o1 < o2) || (o1 == o2 && p1 < p2);
        float s2v = lt2 ? o1 : o2; int s2i = lt2 ? p1 : p2;
        float4 out;
        out.x = f1;  out.y = __int_as_float(g1);
        out.z = s2v; out.w = __int_as_float(s2i);
        pairs[(size_t)j * NROWS + mBase + tid] = out;   // [j][row] layout, coalesced
    }
}

// ---------------- kernel 3: merge 32 tile-top-2 pairs -> top-4 indices ----------------
__global__ __launch_bounds__(256) void merge_kernel(const float4* __restrict__ pairs,
                                                    int* __restrict__ top4) {
    const int row = blockIdx.x * 256 + threadIdx.x;
    float tv[4] = { INFINITY, INFINITY, INFINITY, INFINITY };
    int   tk[4] = { 0x7FFFFFFF, 0x7FFFFFFF, 0x7FFFFFFF, 0x7FFFFFFF };
    for (int j = 0; j < NJT; ++j) {
        float4 p = pairs[(size_t)j * NROWS + row];
        #pragma unroll
        for (int h = 0; h < 2; ++h) {
            float v = h ? p.z : p.x;
            int   k = __float_as_int(h ? p.w : p.y);
            if (v < tv[3] || (v == tv[3] && k < tk[3])) {
                tv[3] = v; tk[3] = k;
                #pragma unroll
                for (int t = 3; t > 0; --t) {
                    bool lt = (tv[t] < tv[t-1]) || (tv[t] == tv[t-1] && tk[t] < tk[t-1]);
                    if (lt) {
                        float fv = tv[t]; tv[t] = tv[t-1]; tv[t-1] = fv;
                        int   fk = tk[t]; tk[t] = tk[t-1]; tk[t-1] = fk;
                    }
                }
            }
        }
    }
    #pragma unroll
    for (int t = 0; t < 4; ++t) top4[(size_t)row * 4 + t] = tk[t];
}

// ---------------- kernel 4: rescore with R1's exact fp32 recipe + gather + loss ----------------
__global__ __launch_bounds__(256) void rescore_kernel(const float* __restrict__ x,
                                                      const float* __restrict__ cb,
                                                      const float* __restrict__ csq,
                                                      const int* __restrict__ top4,
                                                      float* __restrict__ out,
                                                      float* __restrict__ partial) {
    __shared__ float sx[64 * 256];   // 64 rows of x, raw fp32
    __shared__ float rv[64][4];
    __shared__ int   rk[64][4];
    __shared__ int   pick[64];
    __shared__ float sred[256];

    const int tid = threadIdx.x;
    const int rowBase = blockIdx.x * 64;
    const float4* x4 = (const float4*)x;
    const float4* c4 = (const float4*)cb;

    #pragma unroll
    for (int i = 0; i < 16; ++i) {
        int g = tid + i * 256;
        ((float4*)sx)[g] = x4[(size_t)rowBase * 64 + g];
    }
    __syncthreads();

    // one thread per (row, candidate): serial fmaf chain, ascending d (bit-identical to R1)
    {
        const int r = tid >> 2, ci = tid & 3;
        const int k = top4[(size_t)(rowBase + r) * 4 + ci];
        const float4* cr = c4 + (size_t)k * 64;
        const float4* xr = (const float4*)sx + r * 64;
        float acc = 0.f;
        for (int d4 = 0; d4 < 64; ++d4) {
            float4 cv = cr[d4];
            float4 xv = xr[d4];
            acc = fmaf(xv.x, cv.x, acc);
            acc = fmaf(xv.y, cv.y, acc);
            acc = fmaf(xv.z, cv.z, acc);
            acc = fmaf(xv.w, cv.w, acc);
        }
        float cs = csq[k];
        float v = cs - 2.0f * acc;
        rv[r][ci] = v;
        rk[r][ci] = k;
    }
    __syncthreads();

    if (tid < 64) {
        float bv = rv[tid][0];
        int   bi = rk[tid][0];
        #pragma unroll
        for (int t = 1; t < 4; ++t) {
            float v = rv[tid][t];
            int  ii = rk[tid][t];
            if (v < bv || (v == bv && ii < bi)) { bv = v; bi = ii; }
        }
        pick[tid] = bi;
    }
    __syncthreads();

    float s = 0.f;
    #pragma unroll
    for (int i = 0; i < 16; ++i) {
        int g = tid + i * 256;
        int r = g >> 6, col = g & 63;
        int k = pick[r];
        float4 cv = c4[(size_t)k * 64 + col];
        float4 xv = ((const float4*)sx)[g];
        ((float4*)out)[(size_t)rowBase * 64 + g] = cv;
        float dx = cv.x - xv.x, dy = cv.y - xv.y, dz = cv.z - xv.z, dw = cv.w - xv.w;
        s += dx * dx + dy * dy + dz * dz + dw * dw;
    }
    sred[tid] = s;
    __syncthreads();
    for (int off = 128; off > 0; off >>= 1) {
        if (tid < off) sred[tid] += sred[tid + off];
        __syncthreads();
    }
    if (tid == 0) partial[blockIdx.x] = sred[0];
}

// ---------------- kernel 5: finalize loss ----------------
__global__ __launch_bounds__(256) void finalize_kernel(const float* __restrict__ partial,
                                                       float* __restrict__ loss_out) {
    __shared__ float sred[256];
    const int tid = threadIdx.x;
    float s = 0.f;
    for (int i = tid; i < 512; i += 256) s += partial[i];
    sred[tid] = s;
    __syncthreads();
    for (int off = 128; off > 0; off >>= 1) {
        if (tid < off) sred[tid] += sred[tid + off];
        __syncthreads();
    }
    if (tid == 0) loss_out[0] = sred[0] * 1.25f / 8388608.0f;
}

extern "C" void kernel_launch(void* const* d_in, const int* in_sizes, int n_in,
                              void* d_out, int out_size, void* d_ws, size_t ws_size,
                              hipStream_t stream) {
    const float* x  = (const float*)d_in[0];
    const float* cb = (const float*)d_in[1];
    float* out = (float*)d_out;

    char* ws = (char*)d_ws;
    unsigned short* A2 = (unsigned short*)ws;                          // 32 MB
    unsigned short* B2 = (unsigned short*)(ws + 33554432);             // 4 MB
    float* csq         = (float*)(ws + 33554432 + 4194304);            // 16 KB
    int*   top4        = (int*)(ws + 33554432 + 4194304 + 16384);      // 512 KB
    float* partial     = (float*)(ws + 33554432 + 4194304 + 16384 + 524288); // 2 KB

    // pairs scratch lives in d_out (16 MB), fully overwritten by rescore afterwards
    float4* pairs = (float4*)d_out;

    conv_kernel<<<NROWS * 64 / 256, 256, 0, stream>>>(x, A2);     // 8192 blocks
    conv_kernel<<<KCODES * 64 / 256, 256, 0, stream>>>(cb, B2);   // 1024 blocks
    csq_kernel<<<KCODES / 256, 256, 0, stream>>>(cb, csq);
    gemm_top2_kernel<<<(NROWS / BM) * NJT, 256, 0, stream>>>(A2, B2, csq, pairs);
    merge_kernel<<<NROWS / 256, 256, 0, stream>>>(pairs, top4);
    rescore_kernel<<<NROWS / 64, 256, 0, stream>>>(x, cb, csq, top4, out, partial);
    finalize_kernel<<<1, 256, 0, stream>>>(partial, out + 8388608);
}

// Round 7
// 373.769 us; speedup vs baseline: 2.2245x; 1.0445x over previous
//
#include <hip/hip_runtime.h>

#define KCODES 4096
#define NROWS  32768
#define DIM    256           // K (plain bf16)
#define BM     128
#define BN     128
#define BK     64
#define NKT    (DIM / BK)    // 4
#define NJB    4             // j-tiles per block
#define NJG    (KCODES / (BN * NJB))   // 8 j-groups

typedef __attribute__((ext_vector_type(8))) short  short8;
typedef __attribute__((ext_vector_type(4))) float  float4v;

__device__ inline unsigned short f2bf(float f) {
    unsigned u = __float_as_uint(f);
    unsigned r = (u >> 16) & 1u;
    return (unsigned short)((u + 0x7FFFu + r) >> 16);   // RNE
}
__device__ inline void load_lds16(const void* g, void* l) {
    __builtin_amdgcn_global_load_lds((const __attribute__((address_space(1))) void*)g,
                                     (__attribute__((address_space(3))) void*)l, 16, 0, 0);
}

// ---------------- kernel 0: codebook squared norms — VERBATIM R1 recipe ----------------
__global__ __launch_bounds__(256) void csq_kernel(const float* __restrict__ cb,
                                                  float* __restrict__ csq) {
    int code = blockIdx.x * 256 + threadIdx.x;
    if (code < KCODES) {
        const float4* row = (const float4*)(cb + (size_t)code * DIM);
        float s = 0.f;
        #pragma unroll 8
        for (int i = 0; i < DIM / 4; ++i) {
            float4 v = row[i];
            s += v.x * v.x + v.y * v.y + v.z * v.z + v.w * v.w;
        }
        csq[code] = s;
    }
}

// ---------------- kernel 1: x and cb -> bf16 planes (fused, one launch) ----------------
__global__ __launch_bounds__(256) void conv_kernel(const float* __restrict__ x,
                                                   const float* __restrict__ cb,
                                                   unsigned short* __restrict__ A2,
                                                   unsigned short* __restrict__ B2) {
    const int bid = blockIdx.x;
    const float4* src; ushort4* dst; int idx;
    if (bid < NROWS * 64 / 256) {            // 8192 A-blocks
        idx = bid * 256 + threadIdx.x;
        src = (const float4*)x; dst = (ushort4*)A2;
    } else {                                  // 1024 B-blocks
        idx = (bid - NROWS * 64 / 256) * 256 + threadIdx.x;
        src = (const float4*)cb; dst = (ushort4*)B2;
    }
    float4 v = src[idx];
    ushort4 h = { f2bf(v.x), f2bf(v.y), f2bf(v.z), f2bf(v.w) };
    dst[idx] = h;
}

// ---------------- kernel 2: K=256 bf16 GEMM, 4 j-tiles/block, running top-2 ----------------
// grid = 2048: jg = bid & 7 (j-group of 4 N-tiles), mB = bid >> 3
__global__ __launch_bounds__(256, 3) void gemm_top2_kernel(const unsigned short* __restrict__ A2,
                                                           const unsigned short* __restrict__ B2,
                                                           const float* __restrict__ csq,
                                                           float4* __restrict__ pairs) {
    __shared__ unsigned short sA[BM * BK];   // 16 KB, slot = r*8 + (kg ^ (r&7)), 8 bf16/slot
    __shared__ unsigned short sB[BN * BK];
    __shared__ float sV1[2][BM]; __shared__ int sI1[2][BM];
    __shared__ float sV2[2][BM]; __shared__ int sI2[2][BM];

    const int tid = threadIdx.x;
    const int lane = tid & 63, wid = tid >> 6;
    const int wm = wid >> 1, wn = wid & 1;
    const int c = lane & 15, q = lane >> 4;
    const int jg = blockIdx.x & (NJG - 1);
    const int mB = blockIdx.x >> 3;
    const int mBase = mB * BM;

    // staging descriptors: 4 A-slots + 4 B-slots per lane (XOR-swizzled LDS layout)
    unsigned gA[4], gBrel[4];
    int ldsOff[4];
    #pragma unroll
    for (int i = 0; i < 4; ++i) {
        int s  = wid * 256 + i * 64 + lane;   // slot 0..1023
        int r  = s >> 3, kgp = s & 7;
        int kg = kgp ^ (r & 7);
        gA[i]    = (unsigned)(mBase + r) * DIM + kg * 8;
        gBrel[i] = (unsigned)r * DIM + kg * 8;
        ldsOff[i] = (wid * 256 + i * 64) * 8;  // wave-uniform ushort offset
    }

    // running per-lane top-2 for the 16 (mi,r) row-slots, carried across j-tiles
    float rv1[16], rv2[16]; int ri1[16], ri2[16];
    #pragma unroll
    for (int s = 0; s < 16; ++s) { rv1[s] = INFINITY; rv2[s] = INFINITY; ri1[s] = 0x7FFFFFFF; ri2[s] = 0x7FFFFFFF; }

    for (int jj = 0; jj < NJB; ++jj) {
        const int jBase = (jg * NJB + jj) * BN;
        float4v acc[4][4];
        #pragma unroll
        for (int mi = 0; mi < 4; ++mi)
            #pragma unroll
            for (int ni = 0; ni < 4; ++ni)
                #pragma unroll
                for (int e = 0; e < 4; ++e) acc[mi][ni][e] = 0.f;

        for (int kt = 0; kt < NKT; ++kt) {
            const int kOff = kt * BK;
            #pragma unroll
            for (int i = 0; i < 4; ++i) {
                load_lds16(A2 + gA[i] + kOff, &sA[ldsOff[i]]);
                load_lds16(B2 + (size_t)jBase * DIM + gBrel[i] + kOff, &sB[ldsOff[i]]);
            }
            __syncthreads();   // vmcnt drain + barrier

            #pragma unroll
            for (int ks = 0; ks < 2; ++ks) {
                short8 aF[4], bF[4];
                #pragma unroll
                for (int mi = 0; mi < 4; ++mi) {
                    int r  = wm * 64 + mi * 16 + c;
                    int kg = ks * 4 + q;
                    aF[mi] = *(const short8*)&sA[(r * 8 + (kg ^ (r & 7))) * 8];
                }
                #pragma unroll
                for (int ni = 0; ni < 4; ++ni) {
                    int r  = wn * 64 + ni * 16 + c;
                    int kg = ks * 4 + q;
                    bF[ni] = *(const short8*)&sB[(r * 8 + (kg ^ (r & 7))) * 8];
                }
                #pragma unroll
                for (int mi = 0; mi < 4; ++mi)
                    #pragma unroll
                    for (int ni = 0; ni < 4; ++ni)
                        acc[mi][ni] = __builtin_amdgcn_mfma_f32_16x16x32_bf16(aF[mi], bF[ni], acc[mi][ni], 0, 0, 0);
            }
            __syncthreads();   // protect LDS before next stage
        }

        // ---- per-j epilogue: dist = csq - 2*dot ; update running top-2 (ascending k order) ----
        float cs[4];
        #pragma unroll
        for (int ni = 0; ni < 4; ++ni) cs[ni] = csq[jBase + wn * 64 + ni * 16 + c];
        #pragma unroll
        for (int mi = 0; mi < 4; ++mi)
            #pragma unroll
            for (int r = 0; r < 4; ++r) {
                const int s = mi * 4 + r;
                #pragma unroll
                for (int ni = 0; ni < 4; ++ni) {
                    float d = fmaf(-2.f, acc[mi][ni][r], cs[ni]);
                    int   k = jBase + wn * 64 + ni * 16 + c;
                    bool f1 = d < rv1[s];
                    bool f2 = d < rv2[s];
                    rv2[s] = f1 ? rv1[s] : (f2 ? d : rv2[s]);
                    ri2[s] = f1 ? ri1[s] : (f2 ? k : ri2[s]);
                    rv1[s] = f1 ? d : rv1[s];
                    ri1[s] = f1 ? k : ri1[s];
                }
            }
    }

    // ---- once per block: butterfly lex-merge of top-2 over the 16 c-lanes ----
    #pragma unroll
    for (int s = 0; s < 16; ++s) {
        float a1 = rv1[s], a2 = rv2[s]; int b1 = ri1[s], b2 = ri2[s];
        #pragma unroll
        for (int m = 1; m < 16; m <<= 1) {
            float w1 = __shfl_xor(a1, m), w2 = __shfl_xor(a2, m);
            int   j1 = __shfl_xor(b1, m), j2 = __shfl_xor(b2, m);
            bool lt = (w1 < a1) || (w1 == a1 && j1 < b1);
            float f1v = lt ? w1 : a1;  int g1 = lt ? j1 : b1;
            float o1 = lt ? a1 : w1;   int p1 = lt ? b1 : j1;
            float o2 = lt ? w2 : a2;   int p2 = lt ? j2 : b2;
            bool lt2 = (o1 < o2) || (o1 == o2 && p1 < p2);
            a1 = f1v; b1 = g1;
            a2 = lt2 ? o1 : o2; b2 = lt2 ? p1 : p2;
        }
        if (c == 0) {
            int row = wm * 64 + (s >> 2) * 16 + q * 4 + (s & 3);
            sV1[wn][row] = a1; sI1[wn][row] = b1;
            sV2[wn][row] = a2; sI2[wn][row] = b2;
        }
    }
    __syncthreads();

    // merge the two code-halves, write (v1,i1,v2,i2) per row for this j-group
    if (tid < BM) {
        float a1 = sV1[0][tid], a2 = sV2[0][tid];
        int   b1 = sI1[0][tid], b2 = sI2[0][tid];
        float w1 = sV1[1][tid], w2 = sV2[1][tid];
        int   j1 = sI1[1][tid], j2 = sI2[1][tid];
        bool lt = (w1 < a1) || (w1 == a1 && j1 < b1);
        float f1 = lt ? w1 : a1;  int g1 = lt ? j1 : b1;
        float o1 = lt ? a1 : w1;  int p1 = lt ? b1 : j1;
        float o2 = lt ? w2 : a2;  int p2 = lt ? j2 : b2;
        bool lt2 = (o1 < o2) || (o1 == o2 && p1 < p2);
        float s2v = lt2 ? o1 : o2; int s2i = lt2 ? p1 : p2;
        float4 out;
        out.x = f1;  out.y = __int_as_float(g1);
        out.z = s2v; out.w = __int_as_float(s2i);
        pairs[(size_t)jg * NROWS + mBase + tid] = out;   // [jg][row], coalesced
    }
}

// ---------------- kernel 3: merge 8 group-top-2 pairs -> top-4 indices ----------------
__global__ __launch_bounds__(256) void merge_kernel(const float4* __restrict__ pairs,
                                                    int* __restrict__ top4) {
    const int row = blockIdx.x * 256 + threadIdx.x;
    float tv[4] = { INFINITY, INFINITY, INFINITY, INFINITY };
    int   tk[4] = { 0x7FFFFFFF, 0x7FFFFFFF, 0x7FFFFFFF, 0x7FFFFFFF };
    for (int j = 0; j < NJG; ++j) {
        float4 p = pairs[(size_t)j * NROWS + row];
        #pragma unroll
        for (int h = 0; h < 2; ++h) {
            float v = h ? p.z : p.x;
            int   k = __float_as_int(h ? p.w : p.y);
            if (v < tv[3] || (v == tv[3] && k < tk[3])) {
                tv[3] = v; tk[3] = k;
                #pragma unroll
                for (int t = 3; t > 0; --t) {
                    bool lt = (tv[t] < tv[t-1]) || (tv[t] == tv[t-1] && tk[t] < tk[t-1]);
                    if (lt) {
                        float fv = tv[t]; tv[t] = tv[t-1]; tv[t-1] = fv;
                        int   fk = tk[t]; tk[t] = tk[t-1]; tk[t-1] = fk;
                    }
                }
            }
        }
    }
    #pragma unroll
    for (int t = 0; t < 4; ++t) top4[(size_t)row * 4 + t] = tk[t];
}

// ---------------- kernel 4: rescore with R1's exact fp32 recipe + gather + loss ----------------
__global__ __launch_bounds__(256) void rescore_kernel(const float* __restrict__ x,
                                                      const float* __restrict__ cb,
                                                      const float* __restrict__ csq,
                                                      const int* __restrict__ top4,
                                                      float* __restrict__ out,
                                                      float* __restrict__ partial) {
    __shared__ float sx[64 * 256];   // 64 rows of x, raw fp32
    __shared__ float rv[64][4];
    __shared__ int   rk[64][4];
    __shared__ int   pick[64];
    __shared__ float sred[256];

    const int tid = threadIdx.x;
    const int rowBase = blockIdx.x * 64;
    const float4* x4 = (const float4*)x;
    const float4* c4 = (const float4*)cb;

    #pragma unroll
    for (int i = 0; i < 16; ++i) {
        int g = tid + i * 256;
        ((float4*)sx)[g] = x4[(size_t)rowBase * 64 + g];
    }
    __syncthreads();

    // one thread per (row, candidate): serial fmaf chain, ascending d (bit-identical to R1)
    {
        const int r = tid >> 2, ci = tid & 3;
        const int k = top4[(size_t)(rowBase + r) * 4 + ci];
        const float4* cr = c4 + (size_t)k * 64;
        const float4* xr = (const float4*)sx + r * 64;
        float acc = 0.f;
        for (int d4 = 0; d4 < 64; ++d4) {
            float4 cv = cr[d4];
            float4 xv = xr[d4];
            acc = fmaf(xv.x, cv.x, acc);
            acc = fmaf(xv.y, cv.y, acc);
            acc = fmaf(xv.z, cv.z, acc);
            acc = fmaf(xv.w, cv.w, acc);
        }
        float cs = csq[k];
        float v = cs - 2.0f * acc;
        rv[r][ci] = v;
        rk[r][ci] = k;
    }
    __syncthreads();

    if (tid < 64) {
        float bv = rv[tid][0];
        int   bi = rk[tid][0];
        #pragma unroll
        for (int t = 1; t < 4; ++t) {
            float v = rv[tid][t];
            int  ii = rk[tid][t];
            if (v < bv || (v == bv && ii < bi)) { bv = v; bi = ii; }
        }
        pick[tid] = bi;
    }
    __syncthreads();

    float s = 0.f;
    #pragma unroll
    for (int i = 0; i < 16; ++i) {
        int g = tid + i * 256;
        int r = g >> 6, col = g & 63;
        int k = pick[r];
        float4 cv = c4[(size_t)k * 64 + col];
        float4 xv = ((const float4*)sx)[g];
        ((float4*)out)[(size_t)rowBase * 64 + g] = cv;
        float dx = cv.x - xv.x, dy = cv.y - xv.y, dz = cv.z - xv.z, dw = cv.w - xv.w;
        s += dx * dx + dy * dy + dz * dz + dw * dw;
    }
    sred[tid] = s;
    __syncthreads();
    for (int off = 128; off > 0; off >>= 1) {
        if (tid < off) sred[tid] += sred[tid + off];
        __syncthreads();
    }
    if (tid == 0) partial[blockIdx.x] = sred[0];
}

// ---------------- kernel 5: finalize loss ----------------
__global__ __launch_bounds__(256) void finalize_kernel(const float* __restrict__ partial,
                                                       float* __restrict__ loss_out) {
    __shared__ float sred[256];
    const int tid = threadIdx.x;
    float s = 0.f;
    for (int i = tid; i < 512; i += 256) s += partial[i];
    sred[tid] = s;
    __syncthreads();
    for (int off = 128; off > 0; off >>= 1) {
        if (tid < off) sred[tid] += sred[tid + off];
        __syncthreads();
    }
    if (tid == 0) loss_out[0] = sred[0] * 1.25f / 8388608.0f;
}

extern "C" void kernel_launch(void* const* d_in, const int* in_sizes, int n_in,
                              void* d_out, int out_size, void* d_ws, size_t ws_size,
                              hipStream_t stream) {
    const float* x  = (const float*)d_in[0];
    const float* cb = (const float*)d_in[1];
    float* out = (float*)d_out;

    char* ws = (char*)d_ws;
    unsigned short* A2 = (unsigned short*)ws;                          // 16 MB
    unsigned short* B2 = (unsigned short*)(ws + 16777216);             // 2 MB
    float* csq         = (float*)(ws + 16777216 + 2097152);            // 16 KB
    int*   top4        = (int*)(ws + 16777216 + 2097152 + 16384);      // 512 KB
    float* partial     = (float*)(ws + 16777216 + 2097152 + 16384 + 524288); // 2 KB

    // pairs scratch lives in d_out (4 MB used), fully overwritten by rescore afterwards
    float4* pairs = (float4*)d_out;

    conv_kernel<<<(NROWS + KCODES) * 64 / 256, 256, 0, stream>>>(x, cb, A2, B2);
    csq_kernel<<<KCODES / 256, 256, 0, stream>>>(cb, csq);
    gemm_top2_kernel<<<(NROWS / BM) * NJG, 256, 0, stream>>>(A2, B2, csq, pairs);
    merge_kernel<<<NROWS / 256, 256, 0, stream>>>(pairs, top4);
    rescore_kernel<<<NROWS / 64, 256, 0, stream>>>(x, cb, csq, top4, out, partial);
    finalize_kernel<<<1, 256, 0, stream>>>(partial, out + 8388608);
}

// Round 8
// 237.260 us; speedup vs baseline: 3.5044x; 1.5754x over previous
//
#include <hip/hip_runtime.h>

#define KCODES 4096
#define NROWS  32768
#define DIM    256           // K (plain bf16)
#define BM     128
#define BN     128
#define BK     64
#define NKT    (DIM / BK)    // 4 k-chunks
#define NJG    4             // j-groups (grid dim)
#define NJB    (KCODES / (BN * NJG))   // 8 j-tiles per block

typedef __attribute__((ext_vector_type(8))) short  short8;
typedef __attribute__((ext_vector_type(4))) float  float4v;

__device__ inline unsigned short f2bf(float f) {
    unsigned u = __float_as_uint(f);
    unsigned r = (u >> 16) & 1u;
    return (unsigned short)((u + 0x7FFFu + r) >> 16);   // RNE
}
__device__ inline void load_lds16(const void* g, void* l) {
    __builtin_amdgcn_global_load_lds((const __attribute__((address_space(1))) void*)g,
                                     (__attribute__((address_space(3))) void*)l, 16, 0, 0);
}

// ---------------- kernel 0: codebook squared norms — VERBATIM R1 recipe ----------------
__global__ __launch_bounds__(256) void csq_kernel(const float* __restrict__ cb,
                                                  float* __restrict__ csq) {
    int code = blockIdx.x * 256 + threadIdx.x;
    if (code < KCODES) {
        const float4* row = (const float4*)(cb + (size_t)code * DIM);
        float s = 0.f;
        #pragma unroll 8
        for (int i = 0; i < DIM / 4; ++i) {
            float4 v = row[i];
            s += v.x * v.x + v.y * v.y + v.z * v.z + v.w * v.w;
        }
        csq[code] = s;
    }
}

// ---------------- kernel 1: cb -> bf16 plane ----------------
__global__ __launch_bounds__(256) void conv_kernel(const float* __restrict__ cb,
                                                   unsigned short* __restrict__ B2) {
    const int idx = blockIdx.x * 256 + threadIdx.x;
    float4 v = ((const float4*)cb)[idx];
    ushort4 h = { f2bf(v.x), f2bf(v.y), f2bf(v.z), f2bf(v.w) };
    ((ushort4*)B2)[idx] = h;
}

// ---------------- kernel 2: K=256 bf16 GEMM, A resident in LDS, 8 j-tiles/block ----------------
// grid = 1024: jg = bid & 3, mB = bid >> 2
__global__ __launch_bounds__(256, 2) void gemm_top2_kernel(const float* __restrict__ x,
                                                           const unsigned short* __restrict__ B2,
                                                           const float* __restrict__ csq,
                                                           float4* __restrict__ pairs) {
    // A: 4 kt-regions x 1024 slots x 8 bf16; slot(kt, r, kg) = kt*1024 + r*8 + (kg ^ (r&7))
    __shared__ unsigned short sA[4096 * 8];   // 64 KB
    __shared__ unsigned short sB[1024 * 8];   // 16 KB (aliased by merge arrays at the end)

    const int tid = threadIdx.x;
    const int lane = tid & 63, wid = tid >> 6;
    const int wm = wid >> 1, wn = wid & 1;
    const int c = lane & 15, q = lane >> 4;
    const int jg = blockIdx.x & (NJG - 1);
    const int mB = blockIdx.x >> 2;
    const int mBase = mB * BM;

    // ---- stage A once: fp32 x -> bf16 LDS (XOR-swizzled, read layout == R7) ----
    #pragma unroll
    for (int i = 0; i < 16; ++i) {
        int sid = i * 256 + tid;          // slot 0..4095
        int kt  = sid >> 10, rem = sid & 1023;
        int r   = rem >> 3,  kp  = rem & 7;
        int kgl = kp ^ (r & 7);
        const float4* xs = (const float4*)(x + (size_t)(mBase + r) * DIM + kt * BK + kgl * 8);
        float4 v0 = xs[0], v1 = xs[1];
        unsigned short h[8] = { f2bf(v0.x), f2bf(v0.y), f2bf(v0.z), f2bf(v0.w),
                                f2bf(v1.x), f2bf(v1.y), f2bf(v1.z), f2bf(v1.w) };
        *(short8*)&sA[(size_t)sid * 8] = *(short8*)h;
    }

    // B staging descriptors (XOR-swizzled, same as R7)
    unsigned gBrel[4];
    int ldsOff[4];
    #pragma unroll
    for (int i = 0; i < 4; ++i) {
        int s  = wid * 256 + i * 64 + lane;   // slot 0..1023
        int r  = s >> 3, kgp = s & 7;
        int kg = kgp ^ (r & 7);
        gBrel[i]  = (unsigned)r * DIM + kg * 8;
        ldsOff[i] = (wid * 256 + i * 64) * 8;  // wave-uniform ushort offset
    }

    // running per-lane top-2 for the 16 (mi,r) row-slots, carried across all 8 j-tiles
    float rv1[16], rv2[16]; int ri1[16], ri2[16];
    #pragma unroll
    for (int s = 0; s < 16; ++s) { rv1[s] = INFINITY; rv2[s] = INFINITY; ri1[s] = 0x7FFFFFFF; ri2[s] = 0x7FFFFFFF; }

    for (int jj = 0; jj < NJB; ++jj) {
        const int jBase = (jg * NJB + jj) * BN;
        float4v acc[4][4];
        #pragma unroll
        for (int mi = 0; mi < 4; ++mi)
            #pragma unroll
            for (int ni = 0; ni < 4; ++ni)
                #pragma unroll
                for (int e = 0; e < 4; ++e) acc[mi][ni][e] = 0.f;

        for (int kt = 0; kt < NKT; ++kt) {
            const int kOff = kt * BK;
            #pragma unroll
            for (int i = 0; i < 4; ++i)
                load_lds16(B2 + (size_t)jBase * DIM + gBrel[i] + kOff, &sB[ldsOff[i]]);
            __syncthreads();   // vmcnt drain + barrier (also covers A store on kt=0,jj=0)

            #pragma unroll
            for (int ks = 0; ks < 2; ++ks) {
                short8 aF[4], bF[4];
                #pragma unroll
                for (int mi = 0; mi < 4; ++mi) {
                    int r  = wm * 64 + mi * 16 + c;
                    int kg = ks * 4 + q;
                    aF[mi] = *(const short8*)&sA[(size_t)(kt * 1024 + r * 8 + (kg ^ (r & 7))) * 8];
                }
                #pragma unroll
                for (int ni = 0; ni < 4; ++ni) {
                    int r  = wn * 64 + ni * 16 + c;
                    int kg = ks * 4 + q;
                    bF[ni] = *(const short8*)&sB[(r * 8 + (kg ^ (r & 7))) * 8];
                }
                #pragma unroll
                for (int mi = 0; mi < 4; ++mi)
                    #pragma unroll
                    for (int ni = 0; ni < 4; ++ni)
                        acc[mi][ni] = __builtin_amdgcn_mfma_f32_16x16x32_bf16(aF[mi], bF[ni], acc[mi][ni], 0, 0, 0);
            }
            __syncthreads();   // protect sB before next stage
        }

        // ---- per-j epilogue: dist = csq - 2*dot ; update running top-2 (ascending k) ----
        float cs[4];
        #pragma unroll
        for (int ni = 0; ni < 4; ++ni) cs[ni] = csq[jBase + wn * 64 + ni * 16 + c];
        #pragma unroll
        for (int mi = 0; mi < 4; ++mi)
            #pragma unroll
            for (int r = 0; r < 4; ++r) {
                const int s = mi * 4 + r;
                #pragma unroll
                for (int ni = 0; ni < 4; ++ni) {
                    float d = fmaf(-2.f, acc[mi][ni][r], cs[ni]);
                    int   k = jBase + wn * 64 + ni * 16 + c;
                    bool f1 = d < rv1[s];
                    bool f2 = d < rv2[s];
                    rv2[s] = f1 ? rv1[s] : (f2 ? d : rv2[s]);
                    ri2[s] = f1 ? ri1[s] : (f2 ? k : ri2[s]);
                    rv1[s] = f1 ? d : rv1[s];
                    ri1[s] = f1 ? k : ri1[s];
                }
            }
    }

    // ---- merge scratch aliased over sB (no longer needed) ----
    __syncthreads();
    char* mbase = (char*)sB;
    float (*sV1)[BM] = (float(*)[BM])(mbase);
    int   (*sI1)[BM] = (int  (*)[BM])(mbase + 1024);
    float (*sV2)[BM] = (float(*)[BM])(mbase + 2048);
    int   (*sI2)[BM] = (int  (*)[BM])(mbase + 3072);

    // once per block: butterfly lex-merge of top-2 over the 16 c-lanes
    #pragma unroll
    for (int s = 0; s < 16; ++s) {
        float a1 = rv1[s], a2 = rv2[s]; int b1 = ri1[s], b2 = ri2[s];
        #pragma unroll
        for (int m = 1; m < 16; m <<= 1) {
            float w1 = __shfl_xor(a1, m), w2 = __shfl_xor(a2, m);
            int   j1 = __shfl_xor(b1, m), j2 = __shfl_xor(b2, m);
            bool lt = (w1 < a1) || (w1 == a1 && j1 < b1);
            float f1v = lt ? w1 : a1;  int g1 = lt ? j1 : b1;
            float o1 = lt ? a1 : w1;   int p1 = lt ? b1 : j1;
            float o2 = lt ? w2 : a2;   int p2 = lt ? j2 : b2;
            bool lt2 = (o1 < o2) || (o1 == o2 && p1 < p2);
            a1 = f1v; b1 = g1;
            a2 = lt2 ? o1 : o2; b2 = lt2 ? p1 : p2;
        }
        if (c == 0) {
            int row = wm * 64 + (s >> 2) * 16 + q * 4 + (s & 3);
            sV1[wn][row] = a1; sI1[wn][row] = b1;
            sV2[wn][row] = a2; sI2[wn][row] = b2;
        }
    }
    __syncthreads();

    // merge the two code-halves, write (v1,i1,v2,i2) per row for this j-group
    if (tid < BM) {
        float a1 = sV1[0][tid], a2 = sV2[0][tid];
        int   b1 = sI1[0][tid], b2 = sI2[0][tid];
        float w1 = sV1[1][tid], w2 = sV2[1][tid];
        int   j1 = sI1[1][tid], j2 = sI2[1][tid];
        bool lt = (w1 < a1) || (w1 == a1 && j1 < b1);
        float f1 = lt ? w1 : a1;  int g1 = lt ? j1 : b1;
        float o1 = lt ? a1 : w1;  int p1 = lt ? b1 : j1;
        float o2 = lt ? w2 : a2;  int p2 = lt ? j2 : b2;
        bool lt2 = (o1 < o2) || (o1 == o2 && p1 < p2);
        float s2v = lt2 ? o1 : o2; int s2i = lt2 ? p1 : p2;
        float4 outp;
        outp.x = f1;  outp.y = __int_as_float(g1);
        outp.z = s2v; outp.w = __int_as_float(s2i);
        pairs[(size_t)jg * NROWS + mBase + tid] = outp;   // [jg][row], coalesced
    }
}

// ---------------- kernel 3: merge 4 group-top-2 pairs -> top-4 indices ----------------
__global__ __launch_bounds__(256) void merge_kernel(const float4* __restrict__ pairs,
                                                    int* __restrict__ top4) {
    const int row = blockIdx.x * 256 + threadIdx.x;
    float tv[4] = { INFINITY, INFINITY, INFINITY, INFINITY };
    int   tk[4] = { 0x7FFFFFFF, 0x7FFFFFFF, 0x7FFFFFFF, 0x7FFFFFFF };
    for (int j = 0; j < NJG; ++j) {
        float4 p = pairs[(size_t)j * NROWS + row];
        #pragma unroll
        for (int h = 0; h < 2; ++h) {
            float v = h ? p.z : p.x;
            int   k = __float_as_int(h ? p.w : p.y);
            if (v < tv[3] || (v == tv[3] && k < tk[3])) {
                tv[3] = v; tk[3] = k;
                #pragma unroll
                for (int t = 3; t > 0; --t) {
                    bool lt = (tv[t] < tv[t-1]) || (tv[t] == tv[t-1] && tk[t] < tk[t-1]);
                    if (lt) {
                        float fv = tv[t]; tv[t] = tv[t-1]; tv[t-1] = fv;
                        int   fk = tk[t]; tk[t] = tk[t-1]; tk[t-1] = fk;
                    }
                }
            }
        }
    }
    #pragma unroll
    for (int t = 0; t < 4; ++t) top4[(size_t)row * 4 + t] = tk[t];
}

// ---------------- kernel 4: rescore with R1's exact fp32 recipe + gather + loss ----------------
__global__ __launch_bounds__(256) void rescore_kernel(const float* __restrict__ x,
                                                      const float* __restrict__ cb,
                                                      const float* __restrict__ csq,
                                                      const int* __restrict__ top4,
                                                      float* __restrict__ out,
                                                      float* __restrict__ partial) {
    __shared__ float sx[64 * 256];   // 64 rows of x, raw fp32
    __shared__ float rv[64][4];
    __shared__ int   rk[64][4];
    __shared__ int   pick[64];
    __shared__ float sred[256];

    const int tid = threadIdx.x;
    const int rowBase = blockIdx.x * 64;
    const float4* x4 = (const float4*)x;
    const float4* c4 = (const float4*)cb;

    #pragma unroll
    for (int i = 0; i < 16; ++i) {
        int g = tid + i * 256;
        ((float4*)sx)[g] = x4[(size_t)rowBase * 64 + g];
    }
    __syncthreads();

    // one thread per (row, candidate): serial fmaf chain, ascending d (bit-identical to R1)
    {
        const int r = tid >> 2, ci = tid & 3;
        const int k = top4[(size_t)(rowBase + r) * 4 + ci];
        const float4* cr = c4 + (size_t)k * 64;
        const float4* xr = (const float4*)sx + r * 64;
        float acc = 0.f;
        for (int d4 = 0; d4 < 64; ++d4) {
            float4 cv = cr[d4];
            float4 xv = xr[d4];
            acc = fmaf(xv.x, cv.x, acc);
            acc = fmaf(xv.y, cv.y, acc);
            acc = fmaf(xv.z, cv.z, acc);
            acc = fmaf(xv.w, cv.w, acc);
        }
        float cs = csq[k];
        float v = cs - 2.0f * acc;
        rv[r][ci] = v;
        rk[r][ci] = k;
    }
    __syncthreads();

    if (tid < 64) {
        float bv = rv[tid][0];
        int   bi = rk[tid][0];
        #pragma unroll
        for (int t = 1; t < 4; ++t) {
            float v = rv[tid][t];
            int  ii = rk[tid][t];
            if (v < bv || (v == bv && ii < bi)) { bv = v; bi = ii; }
        }
        pick[tid] = bi;
    }
    __syncthreads();

    float s = 0.f;
    #pragma unroll
    for (int i = 0; i < 16; ++i) {
        int g = tid + i * 256;
        int r = g >> 6, col = g & 63;
        int k = pick[r];
        float4 cv = c4[(size_t)k * 64 + col];
        float4 xv = ((const float4*)sx)[g];
        ((float4*)out)[(size_t)rowBase * 64 + g] = cv;
        float dx = cv.x - xv.x, dy = cv.y - xv.y, dz = cv.z - xv.z, dw = cv.w - xv.w;
        s += dx * dx + dy * dy + dz * dz + dw * dw;
    }
    sred[tid] = s;
    __syncthreads();
    for (int off = 128; off > 0; off >>= 1) {
        if (tid < off) sred[tid] += sred[tid + off];
        __syncthreads();
    }
    if (tid == 0) partial[blockIdx.x] = sred[0];
}

// ---------------- kernel 5: finalize loss ----------------
__global__ __launch_bounds__(256) void finalize_kernel(const float* __restrict__ partial,
                                                       float* __restrict__ loss_out) {
    __shared__ float sred[256];
    const int tid = threadIdx.x;
    float s = 0.f;
    for (int i = tid; i < 512; i += 256) s += partial[i];
    sred[tid] = s;
    __syncthreads();
    for (int off = 128; off > 0; off >>= 1) {
        if (tid < off) sred[tid] += sred[tid + off];
        __syncthreads();
    }
    if (tid == 0) loss_out[0] = sred[0] * 1.25f / 8388608.0f;
}

extern "C" void kernel_launch(void* const* d_in, const int* in_sizes, int n_in,
                              void* d_out, int out_size, void* d_ws, size_t ws_size,
                              hipStream_t stream) {
    const float* x  = (const float*)d_in[0];
    const float* cb = (const float*)d_in[1];
    float* out = (float*)d_out;

    char* ws = (char*)d_ws;
    unsigned short* B2 = (unsigned short*)ws;                          // 2 MB
    float* csq         = (float*)(ws + 2097152);                       // 16 KB
    int*   top4        = (int*)(ws + 2097152 + 16384);                 // 512 KB
    float* partial     = (float*)(ws + 2097152 + 16384 + 524288);      // 2 KB

    // pairs scratch lives in d_out (2 MB used), fully overwritten by rescore afterwards
    float4* pairs = (float4*)d_out;

    conv_kernel<<<KCODES * 64 / 256, 256, 0, stream>>>(cb, B2);
    csq_kernel<<<KCODES / 256, 256, 0, stream>>>(cb, csq);
    gemm_top2_kernel<<<(NROWS / BM) * NJG, 256, 0, stream>>>(x, B2, csq, pairs);
    merge_kernel<<<NROWS / 256, 256, 0, stream>>>(pairs, top4);
    rescore_kernel<<<NROWS / 64, 256, 0, stream>>>(x, cb, csq, top4, out, partial);
    finalize_kernel<<<1, 256, 0, stream>>>(partial, out + 8388608);
}